// Round 1
// baseline (471.782 us; speedup 1.0000x reference)
//
#include <hip/hip_runtime.h>
#include <stdint.h>

// Problem constants
constexpr int Tt = 64;     // time steps per (b,n)
constexpr int Dd = 128;    // model dim
constexpr int BN = 4096;   // B*N blocks

typedef short s16x8 __attribute__((ext_vector_type(8)));
typedef short s16x4 __attribute__((ext_vector_type(4)));
typedef float f32x4 __attribute__((ext_vector_type(4)));

__device__ __forceinline__ short f2bf(float f) {
  uint32_t u = __builtin_bit_cast(uint32_t, f);
  u += 0x7FFFu + ((u >> 16) & 1u);   // RNE
  return (short)(u >> 16);
}

// ---- LDS layout (bytes). All 2D tiles swizzled: byte ^= (row&7)<<4 ----
#define SQ_OFF   0        // query staging [64][128] bf16 (reused as X later)
#define SK_OFF   16384    // key staging   (reused as P buffer later)
#define SV_OFF   32768    // value staging
#define SQC_OFF  49152    // conv-q output [64][128]
#define SKC_OFF  65536    // conv-k output [64][128]
#define SVPT_OFF 81920    // V-proj output TRANSPOSED [128][64]
#define SW_OFF   98304    // weight panel [128][128] (32 KB)
#define SX_OFF   SQ_OFF
#define SP_OFF   SK_OFF   // per-wave P slices: wave*2048, [16][64]
#define LDS_TOTAL 131072

__device__ __forceinline__ int swz256(int row, int colElem) {  // rows of 128 bf16
  return (row << 8) + ((colElem << 1) ^ ((row & 7) << 4));
}
__device__ __forceinline__ int swz128(int row, int colElem) {  // rows of 64 bf16
  return (row << 7) + ((colElem << 1) ^ ((row & 7) << 4));
}

// ---------------- weight prep: fp32 -> bf16 (+ reorder Wq/Wk to [ks][o][i]) ---
__global__ void prep_weights(const float* __restrict__ Wq, const float* __restrict__ Wk,
                             const float* __restrict__ W0, const float* __restrict__ W1,
                             short* __restrict__ ws) {
  int i = blockIdx.x * 256 + threadIdx.x;
  if (i >= 131072) return;
  if (i < 49152) {
    int s = i >> 14, rem = i & 16383, o = rem >> 7, ii = rem & 127;
    ws[i] = f2bf(Wq[(o * 128 + ii) * 3 + s]);
  } else if (i < 98304) {
    int j = i - 49152;
    int s = j >> 14, rem = j & 16383, o = rem >> 7, ii = rem & 127;
    ws[i] = f2bf(Wk[(o * 128 + ii) * 3 + s]);
  } else if (i < 114688) {
    ws[i] = f2bf(W0[i - 98304]);   // [e][d]
  } else {
    ws[i] = f2bf(W1[i - 114688]);  // [e][d]
  }
}

// ---------------- per-block conv/proj GEMM ----------------
// out[t][o] = sum_s sum_i src[t + s + SHIFT][i] * w[s][o][i] + bias[o]
// wave -> (row-block rb = wave>>1, col-half ch = wave&1)
template <int NT, int SHIFT, bool TSTORE>
__device__ __forceinline__ void conv_gemm(unsigned char* smem, int srcOff, int dstOff,
                                          const short* __restrict__ w,
                                          const float* __restrict__ bias,
                                          int tid, int wave, int lane) {
  const int rb = wave >> 1, ch = wave & 1;
  f32x4 acc[4];
#pragma unroll
  for (int c = 0; c < 4; ++c) acc[c] = (f32x4){0.f, 0.f, 0.f, 0.f};

#pragma unroll
  for (int s = 0; s < NT; ++s) {
    // stage 128x128 bf16 weight panel [o][i] into SW
    for (int i = tid; i < 2048; i += 512) {
      int row = i >> 4, ce = (i & 15) << 3;
      *(s16x8*)(smem + SW_OFF + swz256(row, ce)) =
          *(const s16x8*)(w + (s << 14) + (row << 7) + ce);
    }
    __syncthreads();
#pragma unroll
    for (int kk = 0; kk < 4; ++kk) {
      const int tr = rb * 16 + (lane & 15) + s + SHIFT;
      s16x8 af = (s16x8){0, 0, 0, 0, 0, 0, 0, 0};
      if (tr >= 0 && tr < Tt)
        af = *(const s16x8*)(smem + srcOff + swz256(tr, kk * 32 + 8 * (lane >> 4)));
#pragma unroll
      for (int c = 0; c < 4; ++c) {
        s16x8 bf = *(const s16x8*)(smem + SW_OFF +
                                   swz256(ch * 64 + c * 16 + (lane & 15), kk * 32 + 8 * (lane >> 4)));
        acc[c] = __builtin_amdgcn_mfma_f32_16x16x32_bf16(af, bf, acc[c], 0, 0, 0);
      }
    }
    __syncthreads();
  }
  // bias + store bf16
#pragma unroll
  for (int c = 0; c < 4; ++c) {
    const int col = ch * 64 + c * 16 + (lane & 15);
    const float bv = bias[col];
#pragma unroll
    for (int r = 0; r < 4; ++r) {
      const int row = rb * 16 + (lane >> 4) * 4 + r;
      short hv = f2bf(acc[c][r] + bv);
      if (TSTORE)
        *(short*)(smem + dstOff + swz128(col, row));   // placeholder avoided below
      if (TSTORE)
        *(short*)(smem + dstOff + swz128(col, row)) = hv;  // VpT[e][t]
      else
        *(short*)(smem + dstOff + swz256(row, col)) = hv;
    }
  }
}

// ---------------- fused main kernel ----------------
__launch_bounds__(512)
__global__ void fused_attn(const float* __restrict__ query, const float* __restrict__ key,
                           const float* __restrict__ value, const short* __restrict__ wsb,
                           const float* __restrict__ bq, const float* __restrict__ bk,
                           const float* __restrict__ b0, const float* __restrict__ b1,
                           float* __restrict__ out) {
  __shared__ unsigned char smem[LDS_TOTAL];
  const int bn = blockIdx.x;
  const int tid = threadIdx.x;
  const int wave = tid >> 6;
  const int lane = tid & 63;
  const size_t base = (size_t)bn * (Tt * Dd);

  // Phase 0: stage q/k/v fp32 -> bf16 LDS
  {
    const float4* src0 = (const float4*)(query + base);
    const float4* src1 = (const float4*)(key + base);
    const float4* src2 = (const float4*)(value + base);
#pragma unroll
    for (int t3 = 0; t3 < 3; ++t3) {
      const float4* s4 = (t3 == 0) ? src0 : (t3 == 1) ? src1 : src2;
      const int off = (t3 == 0) ? SQ_OFF : (t3 == 1) ? SK_OFF : SV_OFF;
      for (int i = tid; i < 2048; i += 512) {
        float4 v = s4[i];
        int row = i >> 5, col = (i & 31) << 2;
        s16x4 b = {f2bf(v.x), f2bf(v.y), f2bf(v.z), f2bf(v.w)};
        *(s16x4*)(smem + off + swz256(row, col)) = b;
      }
    }
  }
  __syncthreads();

  // Phase 1: conv-q (causal, taps t-2..t), conv-k (sym, t-1..t+1), V-proj
  conv_gemm<3, -2, false>(smem, SQ_OFF, SQC_OFF, wsb + 0,      bq, tid, wave, lane);
  conv_gemm<3, -1, false>(smem, SK_OFF, SKC_OFF, wsb + 49152,  bk, tid, wave, lane);
  conv_gemm<1,  0, true >(smem, SV_OFF, SVPT_OFF, wsb + 98304, b0, tid, wave, lane);
  __syncthreads();  // VpT/Qc/Kc visible to all

  // Phase 2: attention. wave -> (rb = wave&3 row-block of 16 q rows, hh = wave>>2 head half)
  {
    const int rb = wave & 3, hh = wave >> 2;
#pragma unroll
    for (int hi = 0; hi < 4; ++hi) {
      const int h = hh * 4 + hi;
      f32x4 sacc[4];
#pragma unroll
      for (int c = 0; c < 4; ++c) sacc[c] = (f32x4){0.f, 0.f, 0.f, 0.f};
      // QK^T (K=16, zero-padded to 32: lanes >=32 contribute zeros)
      s16x8 af = (s16x8){0, 0, 0, 0, 0, 0, 0, 0};
      if (lane < 32)
        af = *(const s16x8*)(smem + SQC_OFF + swz256(rb * 16 + (lane & 15), h * 16 + 8 * (lane >> 4)));
#pragma unroll
      for (int c = 0; c < 4; ++c) {
        s16x8 bf = (s16x8){0, 0, 0, 0, 0, 0, 0, 0};
        if (lane < 32)
          bf = *(const s16x8*)(smem + SKC_OFF + swz256(c * 16 + (lane & 15), h * 16 + 8 * (lane >> 4)));
        sacc[c] = __builtin_amdgcn_mfma_f32_16x16x32_bf16(af, bf, sacc[c], 0, 0, 0);
      }
      // causal mask + softmax (rows spread over 16 lanes x 4 col-tiles)
      const int r0 = rb * 16 + (lane >> 4) * 4;
      float p[4][4], mx[4], sm[4];
#pragma unroll
      for (int r = 0; r < 4; ++r) mx[r] = -3.0e38f;
#pragma unroll
      for (int c = 0; c < 4; ++c) {
        const int col = c * 16 + (lane & 15);
#pragma unroll
        for (int r = 0; r < 4; ++r) {
          float sv = (col <= r0 + r) ? sacc[c][r] * 0.25f : -3.0e38f;
          p[c][r] = sv;
          mx[r] = fmaxf(mx[r], sv);
        }
      }
#pragma unroll
      for (int off = 1; off < 16; off <<= 1) {
#pragma unroll
        for (int r = 0; r < 4; ++r) mx[r] = fmaxf(mx[r], __shfl_xor(mx[r], off));
      }
#pragma unroll
      for (int r = 0; r < 4; ++r) sm[r] = 0.f;
#pragma unroll
      for (int c = 0; c < 4; ++c) {
#pragma unroll
        for (int r = 0; r < 4; ++r) {
          float e = __expf(p[c][r] - mx[r]);
          p[c][r] = e;
          sm[r] += e;
        }
      }
#pragma unroll
      for (int off = 1; off < 16; off <<= 1) {
#pragma unroll
        for (int r = 0; r < 4; ++r) sm[r] += __shfl_xor(sm[r], off);
      }
      float inv[4];
#pragma unroll
      for (int r = 0; r < 4; ++r) inv[r] = 1.0f / sm[r];
      // store normalized P (bf16) into this wave's slice
      unsigned char* sp = smem + SP_OFF + wave * 2048;
#pragma unroll
      for (int c = 0; c < 4; ++c) {
#pragma unroll
        for (int r = 0; r < 4; ++r)
          *(short*)(sp + swz128((lane >> 4) * 4 + r, c * 16 + (lane & 15))) = f2bf(p[c][r] * inv[r]);
      }
      asm volatile("s_waitcnt lgkmcnt(0)" ::: "memory");
      // PV: X_h (16x16), K=64 over key positions
      f32x4 xacc = (f32x4){0.f, 0.f, 0.f, 0.f};
#pragma unroll
      for (int kc = 0; kc < 2; ++kc) {
        s16x8 pf = *(const s16x8*)(sp + swz128(lane & 15, kc * 32 + 8 * (lane >> 4)));
        s16x8 vf = *(const s16x8*)(smem + SVPT_OFF + swz128(h * 16 + (lane & 15), kc * 32 + 8 * (lane >> 4)));
        xacc = __builtin_amdgcn_mfma_f32_16x16x32_bf16(pf, vf, xacc, 0, 0, 0);
      }
      // store X tile (bf16)
#pragma unroll
      for (int r = 0; r < 4; ++r)
        *(short*)(smem + SX_OFF + swz256(rb * 16 + (lane >> 4) * 4 + r, h * 16 + (lane & 15))) = f2bf(xacc[r]);
      asm volatile("s_waitcnt lgkmcnt(0)" ::: "memory");
    }
  }

  // Phase 3: out = X @ W1^T + b1
  {
    const short* w1 = wsb + 114688;
    for (int i = tid; i < 2048; i += 512) {
      int row = i >> 4, ce = (i & 15) << 3;
      *(s16x8*)(smem + SW_OFF + swz256(row, ce)) = *(const s16x8*)(w1 + (row << 7) + ce);
    }
    __syncthreads();
    const int rb = wave >> 1, ch = wave & 1;
    f32x4 oacc[4];
#pragma unroll
    for (int c = 0; c < 4; ++c) oacc[c] = (f32x4){0.f, 0.f, 0.f, 0.f};
#pragma unroll
    for (int kk = 0; kk < 4; ++kk) {
      s16x8 af = *(const s16x8*)(smem + SX_OFF + swz256(rb * 16 + (lane & 15), kk * 32 + 8 * (lane >> 4)));
#pragma unroll
      for (int c = 0; c < 4; ++c) {
        s16x8 bf = *(const s16x8*)(smem + SW_OFF +
                                   swz256(ch * 64 + c * 16 + (lane & 15), kk * 32 + 8 * (lane >> 4)));
        oacc[c] = __builtin_amdgcn_mfma_f32_16x16x32_bf16(af, bf, oacc[c], 0, 0, 0);
      }
    }
#pragma unroll
    for (int c = 0; c < 4; ++c) {
      const int col = ch * 64 + c * 16 + (lane & 15);
      const float bv = b1[col];
#pragma unroll
      for (int r = 0; r < 4; ++r) {
        const int row = rb * 16 + (lane >> 4) * 4 + r;
        out[base + (size_t)row * Dd + col] = oacc[c][r] + bv;
      }
    }
  }
}

extern "C" void kernel_launch(void* const* d_in, const int* in_sizes, int n_in,
                              void* d_out, int out_size, void* d_ws, size_t ws_size,
                              hipStream_t stream) {
  (void)in_sizes; (void)n_in; (void)out_size; (void)ws_size;
  const float* query = (const float*)d_in[0];
  const float* key   = (const float*)d_in[1];
  const float* value = (const float*)d_in[2];
  // d_in[3] = mask (tril by construction -> causality hardcoded)
  const float* Wq = (const float*)d_in[4];
  const float* bq = (const float*)d_in[5];
  const float* Wk = (const float*)d_in[6];
  const float* bk = (const float*)d_in[7];
  const float* W0 = (const float*)d_in[8];
  const float* b0 = (const float*)d_in[9];
  const float* W1 = (const float*)d_in[10];
  const float* b1 = (const float*)d_in[11];
  float* out = (float*)d_out;
  short* wsb = (short*)d_ws;  // 131072 bf16 = 256 KB

  hipLaunchKernelGGL(prep_weights, dim3(512), dim3(256), 0, stream, Wq, Wk, W0, W1, wsb);
  hipLaunchKernelGGL(fused_attn, dim3(BN), dim3(512), 0, stream,
                     query, key, value, wsb, bq, bk, b0, b1, out);
}

// Round 2
// 249.457 us; speedup vs baseline: 1.8912x; 1.8912x over previous
//
#include <hip/hip_runtime.h>
#include <stdint.h>

// Problem constants
constexpr int Tt = 64;     // time steps per (b,n)
constexpr int Dd = 128;    // model dim
constexpr int BN = 4096;   // B*N blocks

typedef short s16x8 __attribute__((ext_vector_type(8)));
typedef short s16x4 __attribute__((ext_vector_type(4)));
typedef float f32x4 __attribute__((ext_vector_type(4)));

__device__ __forceinline__ short f2bf(float f) {
  uint32_t u = __builtin_bit_cast(uint32_t, f);
  u += 0x7FFFu + ((u >> 16) & 1u);   // RNE
  return (short)(u >> 16);
}

// ---- LDS layout (bytes). 2D tiles swizzled: byte ^= (row&7)<<4 ----
// SQ: q staging -> Qc -> X ; SK: k staging -> Kc ; SV: v staging -> VpT
#define SQ_OFF   0
#define SK_OFF   16384
#define SV_OFF   32768
#define SP_OFF   49152    // per-wave P slices: wave*2048, [16][64]
#define LDS_TOTAL 65536

__device__ __forceinline__ int swz256(int row, int colElem) {  // rows of 128 bf16
  return (row << 8) + ((colElem << 1) ^ ((row & 7) << 4));
}
__device__ __forceinline__ int swz128(int row, int colElem) {  // rows of 64 bf16
  return (row << 7) + ((colElem << 1) ^ ((row & 7) << 4));
}

// ---------------- weight prep: fp32 -> bf16 (+ reorder Wq/Wk to [ks][o][i]) ---
__global__ void prep_weights(const float* __restrict__ Wq, const float* __restrict__ Wk,
                             const float* __restrict__ W0, const float* __restrict__ W1,
                             short* __restrict__ ws) {
  int i = blockIdx.x * 256 + threadIdx.x;
  if (i >= 131072) return;
  if (i < 49152) {
    int s = i >> 14, rem = i & 16383, o = rem >> 7, ii = rem & 127;
    ws[i] = f2bf(Wq[(o * 128 + ii) * 3 + s]);
  } else if (i < 98304) {
    int j = i - 49152;
    int s = j >> 14, rem = j & 16383, o = rem >> 7, ii = rem & 127;
    ws[i] = f2bf(Wk[(o * 128 + ii) * 3 + s]);
  } else if (i < 114688) {
    ws[i] = f2bf(W0[i - 98304]);   // [e][d]
  } else {
    ws[i] = f2bf(W1[i - 114688]);  // [e][d]
  }
}

// ---------------- conv/proj GEMM, wave owns 16 output cols for all 64 rows ----
// out[t][col] = sum_s sum_i src[t + s + SHIFT][i] * w[s][col][i]
// B-fragments loaded DIRECTLY from global (L2-resident weights, zero redundancy)
template <int NT, int SHIFT>
__device__ __forceinline__ void conv_proj(const unsigned char* smem, int srcOff,
                                          const short* __restrict__ w,
                                          int lane, int cb, f32x4 acc[4]) {
#pragma unroll
  for (int rb = 0; rb < 4; ++rb) acc[rb] = (f32x4){0.f, 0.f, 0.f, 0.f};
  const int col = cb * 16 + (lane & 15);
  const int ke = 8 * (lane >> 4);
#pragma unroll
  for (int s = 0; s < NT; ++s) {
    s16x8 bfrag[4];
#pragma unroll
    for (int kk = 0; kk < 4; ++kk)
      bfrag[kk] = *(const s16x8*)(w + (s << 14) + (col << 7) + kk * 32 + ke);
#pragma unroll
    for (int kk = 0; kk < 4; ++kk) {
#pragma unroll
      for (int rb = 0; rb < 4; ++rb) {
        const int tr = rb * 16 + (lane & 15) + s + SHIFT;
        s16x8 af = (s16x8){0, 0, 0, 0, 0, 0, 0, 0};
        if (tr >= 0 && tr < Tt)
          af = *(const s16x8*)(smem + srcOff + swz256(tr, kk * 32 + ke));
        acc[rb] = __builtin_amdgcn_mfma_f32_16x16x32_bf16(af, bfrag[kk], acc[rb], 0, 0, 0);
      }
    }
  }
}

__device__ __forceinline__ void writeback_n(unsigned char* smem, int dstOff,
                                            const f32x4 acc[4], float bv, int lane, int cb) {
  const int col = cb * 16 + (lane & 15);
#pragma unroll
  for (int rb = 0; rb < 4; ++rb)
#pragma unroll
    for (int r = 0; r < 4; ++r) {
      const int row = rb * 16 + (lane >> 4) * 4 + r;
      *(short*)(smem + dstOff + swz256(row, col)) = f2bf(acc[rb][r] + bv);
    }
}

__device__ __forceinline__ void writeback_t(unsigned char* smem, int dstOff,
                                            const f32x4 acc[4], float bv, int lane, int cb) {
  const int col = cb * 16 + (lane & 15);
#pragma unroll
  for (int rb = 0; rb < 4; ++rb)
#pragma unroll
    for (int r = 0; r < 4; ++r) {
      const int row = rb * 16 + (lane >> 4) * 4 + r;
      *(short*)(smem + dstOff + swz128(col, row)) = f2bf(acc[rb][r] + bv);  // [d][t]
    }
}

// ---------------- fused main kernel ----------------
__launch_bounds__(512, 4)
__global__ void fused_attn(const float* __restrict__ query, const float* __restrict__ key,
                           const float* __restrict__ value, const short* __restrict__ wsb,
                           const float* __restrict__ bq, const float* __restrict__ bk,
                           const float* __restrict__ b0, const float* __restrict__ b1,
                           float* __restrict__ out) {
  __shared__ unsigned char smem[LDS_TOTAL];
  const int bn = blockIdx.x;
  const int tid = threadIdx.x;
  const int wave = tid >> 6;
  const int lane = tid & 63;
  const size_t base = (size_t)bn * (Tt * Dd);

  // Phase 0: stage q/k/v fp32 -> bf16 LDS
  {
#pragma unroll
    for (int t3 = 0; t3 < 3; ++t3) {
      const float* sp = (t3 == 0) ? query : (t3 == 1) ? key : value;
      const float4* s4 = (const float4*)(sp + base);
      const int off = (t3 == 0) ? SQ_OFF : (t3 == 1) ? SK_OFF : SV_OFF;
      for (int i = tid; i < 2048; i += 512) {
        float4 v = s4[i];
        int row = i >> 5, col = (i & 31) << 2;
        s16x4 b = {f2bf(v.x), f2bf(v.y), f2bf(v.z), f2bf(v.w)};
        *(s16x4*)(smem + off + swz256(row, col)) = b;
      }
    }
  }
  __syncthreads();  // b1

  const int cb = wave;  // col-block ownership for projections
  f32x4 acc[4];

  // conv-q (causal, taps t-2..t)
  conv_proj<3, -2>(smem, SQ_OFF, wsb + 0, lane, cb, acc);
  __syncthreads();  // b2: all SQ reads done
  writeback_n(smem, SQ_OFF, acc, bq[cb * 16 + (lane & 15)], lane, cb);  // SQ := Qc

  // conv-k (sym, taps t-1..t+1)
  conv_proj<3, -1>(smem, SK_OFF, wsb + 49152, lane, cb, acc);
  __syncthreads();  // b3: all SK reads done (Qc also visible from here on)
  writeback_n(smem, SK_OFF, acc, bk[cb * 16 + (lane & 15)], lane, cb);  // SK := Kc

  // V-projection
  conv_proj<1, 0>(smem, SV_OFF, wsb + 98304, lane, cb, acc);
  __syncthreads();  // b4: all SV reads done
  writeback_t(smem, SV_OFF, acc, b0[cb * 16 + (lane & 15)], lane, cb);  // SV := VpT [d][t]
  __syncthreads();  // b5: Qc/Kc/VpT all visible

  // Phase 2: attention. wave -> (rb = wave&3 row-block of 16 q rows, hh = wave>>2)
  {
    const int rb = wave & 3, hh = wave >> 2;
#pragma unroll
    for (int hi = 0; hi < 4; ++hi) {
      const int h = hh * 4 + hi;
      f32x4 sacc[4];
#pragma unroll
      for (int c = 0; c < 4; ++c) sacc[c] = (f32x4){0.f, 0.f, 0.f, 0.f};
      // QK^T (K=16, zero-padded to 32: lanes >=32 contribute zeros)
      s16x8 af = (s16x8){0, 0, 0, 0, 0, 0, 0, 0};
      if (lane < 32)
        af = *(const s16x8*)(smem + SQ_OFF + swz256(rb * 16 + (lane & 15), h * 16 + 8 * (lane >> 4)));
#pragma unroll
      for (int c = 0; c < 4; ++c) {
        s16x8 bf = (s16x8){0, 0, 0, 0, 0, 0, 0, 0};
        if (lane < 32)
          bf = *(const s16x8*)(smem + SK_OFF + swz256(c * 16 + (lane & 15), h * 16 + 8 * (lane >> 4)));
        sacc[c] = __builtin_amdgcn_mfma_f32_16x16x32_bf16(af, bf, sacc[c], 0, 0, 0);
      }
      // causal mask + softmax (rows spread over 16 lanes x 4 col-tiles)
      const int r0 = rb * 16 + (lane >> 4) * 4;
      float p[4][4], mx[4], sm[4];
#pragma unroll
      for (int r = 0; r < 4; ++r) mx[r] = -3.0e38f;
#pragma unroll
      for (int c = 0; c < 4; ++c) {
        const int col = c * 16 + (lane & 15);
#pragma unroll
        for (int r = 0; r < 4; ++r) {
          float sv = (col <= r0 + r) ? sacc[c][r] * 0.25f : -3.0e38f;
          p[c][r] = sv;
          mx[r] = fmaxf(mx[r], sv);
        }
      }
#pragma unroll
      for (int off = 1; off < 16; off <<= 1) {
#pragma unroll
        for (int r = 0; r < 4; ++r) mx[r] = fmaxf(mx[r], __shfl_xor(mx[r], off));
      }
#pragma unroll
      for (int r = 0; r < 4; ++r) sm[r] = 0.f;
#pragma unroll
      for (int c = 0; c < 4; ++c) {
#pragma unroll
        for (int r = 0; r < 4; ++r) {
          float e = __expf(p[c][r] - mx[r]);
          p[c][r] = e;
          sm[r] += e;
        }
      }
#pragma unroll
      for (int off = 1; off < 16; off <<= 1) {
#pragma unroll
        for (int r = 0; r < 4; ++r) sm[r] += __shfl_xor(sm[r], off);
      }
      float inv[4];
#pragma unroll
      for (int r = 0; r < 4; ++r) inv[r] = 1.0f / sm[r];
      // store normalized P (bf16) into this wave's slice
      unsigned char* sp = smem + SP_OFF + wave * 2048;
#pragma unroll
      for (int c = 0; c < 4; ++c) {
#pragma unroll
        for (int r = 0; r < 4; ++r)
          *(short*)(sp + swz128((lane >> 4) * 4 + r, c * 16 + (lane & 15))) = f2bf(p[c][r] * inv[r]);
      }
      asm volatile("s_waitcnt lgkmcnt(0)" ::: "memory");
      // PV: X_h (16x16), K=64 over key positions
      f32x4 xacc = (f32x4){0.f, 0.f, 0.f, 0.f};
#pragma unroll
      for (int kc = 0; kc < 2; ++kc) {
        s16x8 pf = *(const s16x8*)(sp + swz128(lane & 15, kc * 32 + 8 * (lane >> 4)));
        s16x8 vf = *(const s16x8*)(smem + SV_OFF + swz128(h * 16 + (lane & 15), kc * 32 + 8 * (lane >> 4)));
        xacc = __builtin_amdgcn_mfma_f32_16x16x32_bf16(pf, vf, xacc, 0, 0, 0);
      }
      // store X tile (bf16) over Qc (same-wave region, consumed already)
#pragma unroll
      for (int r = 0; r < 4; ++r)
        *(short*)(smem + SQ_OFF + swz256(rb * 16 + (lane >> 4) * 4 + r, h * 16 + (lane & 15))) = f2bf(xacc[r]);
      asm volatile("s_waitcnt lgkmcnt(0)" ::: "memory");
    }
  }
  __syncthreads();  // b6: X visible

  // Phase 3: out = X @ W1^T + b1 (B-fragments from global)
  {
    const short* w1 = wsb + 114688;
    const int col = cb * 16 + (lane & 15);
    const int ke = 8 * (lane >> 4);
    s16x8 bfrag[4];
#pragma unroll
    for (int kk = 0; kk < 4; ++kk)
      bfrag[kk] = *(const s16x8*)(w1 + (col << 7) + kk * 32 + ke);
    f32x4 oacc[4];
#pragma unroll
    for (int rb = 0; rb < 4; ++rb) oacc[rb] = (f32x4){0.f, 0.f, 0.f, 0.f};
#pragma unroll
    for (int kk = 0; kk < 4; ++kk) {
#pragma unroll
      for (int rb = 0; rb < 4; ++rb) {
        s16x8 af = *(const s16x8*)(smem + SQ_OFF + swz256(rb * 16 + (lane & 15), kk * 32 + ke));
        oacc[rb] = __builtin_amdgcn_mfma_f32_16x16x32_bf16(af, bfrag[kk], oacc[rb], 0, 0, 0);
      }
    }
    const float bv = b1[col];
#pragma unroll
    for (int rb = 0; rb < 4; ++rb)
#pragma unroll
      for (int r = 0; r < 4; ++r) {
        const int row = rb * 16 + (lane >> 4) * 4 + r;
        out[base + (size_t)row * Dd + col] = oacc[rb][r] + bv;
      }
  }
}

extern "C" void kernel_launch(void* const* d_in, const int* in_sizes, int n_in,
                              void* d_out, int out_size, void* d_ws, size_t ws_size,
                              hipStream_t stream) {
  (void)in_sizes; (void)n_in; (void)out_size; (void)ws_size;
  const float* query = (const float*)d_in[0];
  const float* key   = (const float*)d_in[1];
  const float* value = (const float*)d_in[2];
  // d_in[3] = mask (tril by construction -> causality hardcoded)
  const float* Wq = (const float*)d_in[4];
  const float* bq = (const float*)d_in[5];
  const float* Wk = (const float*)d_in[6];
  const float* bk = (const float*)d_in[7];
  const float* W0 = (const float*)d_in[8];
  const float* b0 = (const float*)d_in[9];
  const float* W1 = (const float*)d_in[10];
  const float* b1 = (const float*)d_in[11];
  float* out = (float*)d_out;
  short* wsb = (short*)d_ws;  // 131072 bf16 = 256 KB

  hipLaunchKernelGGL(prep_weights, dim3(512), dim3(256), 0, stream, Wq, Wk, W0, W1, wsb);
  hipLaunchKernelGGL(fused_attn, dim3(BN), dim3(512), 0, stream,
                     query, key, value, wsb, bq, bk, b0, b1, out);
}

// Round 3
// 241.982 us; speedup vs baseline: 1.9497x; 1.0309x over previous
//
#include <hip/hip_runtime.h>
#include <hip/hip_bf16.h>
#include <stdint.h>

// Problem constants
constexpr int Tt = 64;     // time steps per (b,n)
constexpr int Dd = 128;    // model dim
constexpr int BN = 4096;   // B*N blocks

typedef short s16x8 __attribute__((ext_vector_type(8)));
typedef short s16x4 __attribute__((ext_vector_type(4)));
typedef float f32x4 __attribute__((ext_vector_type(4)));

__device__ __forceinline__ short f2bf(float f) {
  return (short)__bfloat16_as_ushort(__float2bfloat16(f));  // native cvt, pk-fusable
}

// ---- LDS layout (bytes). 2D tiles swizzled: byte ^= (row&7)<<4 ----
// SQ/SK: padded staging [68][128] (rows = t+2, rows 0,1,66,67 zero) -> Qc/Kc [64][128] -> X
// SV: v staging [64][128] -> VpT [128][64]
#define SQ_OFF   0
#define SK_OFF   17408
#define SV_OFF   34816
#define SP_OFF   51200    // per-wave P slices: wave*2048, [16][64]
#define LDS_TOTAL 67584

__device__ __forceinline__ int swz256(int row, int colElem) {  // rows of 128 bf16
  return (row << 8) + ((colElem << 1) ^ ((row & 7) << 4));
}
__device__ __forceinline__ int swz128(int row, int colElem) {  // rows of 64 bf16
  return (row << 7) + ((colElem << 1) ^ ((row & 7) << 4));
}
__device__ __forceinline__ int swzP(int row, int colElem) {    // P tile [16][64]
  return (row << 7) + (((colElem << 1) ^ ((row & 7) << 4)) ^ ((row & 8) << 2));
}

// ---------------- weight prep: fp32 -> bf16 (+ reorder Wq/Wk to [ks][o][i]) ---
__global__ void prep_weights(const float* __restrict__ Wq, const float* __restrict__ Wk,
                             const float* __restrict__ W0, const float* __restrict__ W1,
                             short* __restrict__ ws) {
  int i = blockIdx.x * 256 + threadIdx.x;
  if (i >= 131072) return;
  if (i < 49152) {
    int s = i >> 14, rem = i & 16383, o = rem >> 7, ii = rem & 127;
    ws[i] = f2bf(Wq[(o * 128 + ii) * 3 + s]);
  } else if (i < 98304) {
    int j = i - 49152;
    int s = j >> 14, rem = j & 16383, o = rem >> 7, ii = rem & 127;
    ws[i] = f2bf(Wk[(o * 128 + ii) * 3 + s]);
  } else if (i < 114688) {
    ws[i] = f2bf(W0[i - 98304]);   // [e][d]
  } else {
    ws[i] = f2bf(W1[i - 114688]);  // [e][d]
  }
}

// ---------------- fused main kernel ----------------
__launch_bounds__(512, 4)
__global__ void fused_attn(const float* __restrict__ query, const float* __restrict__ key,
                           const float* __restrict__ value, const short* __restrict__ wsb,
                           const float* __restrict__ bq, const float* __restrict__ bk,
                           const float* __restrict__ b0, const float* __restrict__ b1,
                           float* __restrict__ out) {
  __shared__ unsigned char smem[LDS_TOTAL];
  const int bn = blockIdx.x;
  const int tid = threadIdx.x;
  const int wave = tid >> 6;
  const int lane = tid & 63;
  const size_t base = (size_t)bn * (Tt * Dd);

  const int cb = wave;                      // col-block ownership for projections
  const int col = cb * 16 + (lane & 15);
  const int ke = 8 * (lane >> 4);
  const int arow = lane & 15;

  // Phase 0: stage q/k/v fp32 -> bf16 LDS (+2-row zero borders for q/k)
  if (tid < 128) {
    int bufOff = (tid >= 64) ? SK_OFF : SQ_OFF;
    int ri = (tid >> 4) & 3;
    int row = (ri < 2) ? ri : 64 + ri;      // 0,1,66,67
    s16x8 z = {};
    *(s16x8*)(smem + bufOff + swz256(row, (tid & 15) * 8)) = z;
  }
  {
#pragma unroll
    for (int t3 = 0; t3 < 3; ++t3) {
      const float* sp = (t3 == 0) ? query : (t3 == 1) ? key : value;
      const float4* s4 = (const float4*)(sp + base);
      const int off = (t3 == 0) ? SQ_OFF : (t3 == 1) ? SK_OFF : SV_OFF;
      const int rshift = (t3 == 2) ? 0 : 2;
      for (int i = tid; i < 2048; i += 512) {
        float4 v = s4[i];
        int row = (i >> 5) + rshift, c4 = (i & 31) << 2;
        s16x4 b = {f2bf(v.x), f2bf(v.y), f2bf(v.z), f2bf(v.w)};
        *(s16x4*)(smem + off + swz256(row, c4)) = b;
      }
    }
  }
  __syncthreads();  // b1

  // Phase 1 (merged): conv-q (taps t-2..t), conv-k (taps t-1..t+1), V-proj.
  // B-fragments direct from global (L2-resident); A-frags from padded LDS, unconditional.
  f32x4 aq[4], ak[4], av[4];
#pragma unroll
  for (int rb = 0; rb < 4; ++rb) {
    aq[rb] = (f32x4){0.f, 0.f, 0.f, 0.f};
    ak[rb] = (f32x4){0.f, 0.f, 0.f, 0.f};
    av[rb] = (f32x4){0.f, 0.f, 0.f, 0.f};
  }
  const short* wq = wsb;
  const short* wk = wsb + 49152;
  const short* wv = wsb + 98304;
  const short* w1 = wsb + 114688;

#pragma unroll
  for (int s = 0; s < 3; ++s) {
    s16x8 bq8[4], bk8[4];
#pragma unroll
    for (int kk = 0; kk < 4; ++kk) {
      bq8[kk] = *(const s16x8*)(wq + (s << 14) + (col << 7) + kk * 32 + ke);
      bk8[kk] = *(const s16x8*)(wk + (s << 14) + (col << 7) + kk * 32 + ke);
    }
#pragma unroll
    for (int kk = 0; kk < 4; ++kk) {
#pragma unroll
      for (int rb = 0; rb < 4; ++rb) {
        s16x8 afq = *(const s16x8*)(smem + SQ_OFF + swz256(rb * 16 + arow + s, kk * 32 + ke));
        aq[rb] = __builtin_amdgcn_mfma_f32_16x16x32_bf16(afq, bq8[kk], aq[rb], 0, 0, 0);
        s16x8 afk = *(const s16x8*)(smem + SK_OFF + swz256(rb * 16 + arow + s + 1, kk * 32 + ke));
        ak[rb] = __builtin_amdgcn_mfma_f32_16x16x32_bf16(afk, bk8[kk], ak[rb], 0, 0, 0);
      }
    }
  }
  {
    s16x8 bv8[4];
#pragma unroll
    for (int kk = 0; kk < 4; ++kk)
      bv8[kk] = *(const s16x8*)(wv + (col << 7) + kk * 32 + ke);
#pragma unroll
    for (int kk = 0; kk < 4; ++kk) {
#pragma unroll
      for (int rb = 0; rb < 4; ++rb) {
        s16x8 afv = *(const s16x8*)(smem + SV_OFF + swz256(rb * 16 + arow, kk * 32 + ke));
        av[rb] = __builtin_amdgcn_mfma_f32_16x16x32_bf16(afv, bv8[kk], av[rb], 0, 0, 0);
      }
    }
  }
  __syncthreads();  // b2: all staging reads done

  // writebacks: SQ := Qc [t][d] (rows 0..63), SK := Kc, SV := VpT [d][t]
  {
    const float bqv = bq[col], bkv = bk[col], b0v = b0[col];
#pragma unroll
    for (int rb = 0; rb < 4; ++rb) {
#pragma unroll
      for (int r = 0; r < 4; ++r) {
        const int row = rb * 16 + (lane >> 4) * 4 + r;
        *(short*)(smem + SQ_OFF + swz256(row, col)) = f2bf(aq[rb][r] + bqv);
        *(short*)(smem + SK_OFF + swz256(row, col)) = f2bf(ak[rb][r] + bkv);
        *(short*)(smem + SV_OFF + swz128(col, row)) = f2bf(av[rb][r] + b0v);
      }
    }
  }
  // prefetch W1 B-fragments (used in phase 3) while barrier + attention run
  s16x8 w1f[4];
#pragma unroll
  for (int kk = 0; kk < 4; ++kk)
    w1f[kk] = *(const s16x8*)(w1 + (col << 7) + kk * 32 + ke);
  __syncthreads();  // b3: Qc/Kc/VpT visible

  // Phase 2: attention. wave -> (rb = wave&3 row-block of 16 q rows, hh = wave>>2)
  {
    const int rb = wave & 3, hh = wave >> 2;
    const int sel = lane >> 5;  // lanes >=32 -> k=16..31 slots: read zero pad row 66
    const int aRow = sel ? 66 : (rb * 16 + arow);
    int bRow[4];
#pragma unroll
    for (int c = 0; c < 4; ++c) bRow[c] = sel ? 66 : (c * 16 + arow);
    unsigned char* sp = smem + SP_OFF + wave * 2048;
#pragma unroll
    for (int hi = 0; hi < 4; ++hi) {
      const int h = hh * 4 + hi;
      f32x4 sacc[4];
#pragma unroll
      for (int c = 0; c < 4; ++c) sacc[c] = (f32x4){0.f, 0.f, 0.f, 0.f};
      // QK^T (K=16 in k-slots 0..15; lanes>=32 read zeros from pad row)
      s16x8 af = *(const s16x8*)(smem + SQ_OFF + swz256(aRow, h * 16 + ke));
#pragma unroll
      for (int c = 0; c < 4; ++c) {
        s16x8 bf = *(const s16x8*)(smem + SK_OFF + swz256(bRow[c], h * 16 + ke));
        sacc[c] = __builtin_amdgcn_mfma_f32_16x16x32_bf16(af, bf, sacc[c], 0, 0, 0);
      }
      // causal mask + softmax (rows spread over 16 lanes x 4 col-tiles)
      const int r0 = rb * 16 + (lane >> 4) * 4;
      float p[4][4], mx[4], sm[4];
#pragma unroll
      for (int r = 0; r < 4; ++r) mx[r] = -3.0e38f;
#pragma unroll
      for (int c = 0; c < 4; ++c) {
        const int scol = c * 16 + (lane & 15);
#pragma unroll
        for (int r = 0; r < 4; ++r) {
          float sv = (scol <= r0 + r) ? sacc[c][r] * 0.25f : -3.0e38f;
          p[c][r] = sv;
          mx[r] = fmaxf(mx[r], sv);
        }
      }
#pragma unroll
      for (int off = 1; off < 16; off <<= 1) {
#pragma unroll
        for (int r = 0; r < 4; ++r) mx[r] = fmaxf(mx[r], __shfl_xor(mx[r], off));
      }
#pragma unroll
      for (int r = 0; r < 4; ++r) sm[r] = 0.f;
#pragma unroll
      for (int c = 0; c < 4; ++c) {
#pragma unroll
        for (int r = 0; r < 4; ++r) {
          float e = __expf(p[c][r] - mx[r]);
          p[c][r] = e;
          sm[r] += e;
        }
      }
#pragma unroll
      for (int off = 1; off < 16; off <<= 1) {
#pragma unroll
        for (int r = 0; r < 4; ++r) sm[r] += __shfl_xor(sm[r], off);
      }
      float inv[4];
#pragma unroll
      for (int r = 0; r < 4; ++r) inv[r] = 1.0f / sm[r];
      // store UNNORMALIZED P (bf16); normalization folded into X after PV
#pragma unroll
      for (int c = 0; c < 4; ++c) {
#pragma unroll
        for (int r = 0; r < 4; ++r)
          *(short*)(sp + swzP((lane >> 4) * 4 + r, c * 16 + (lane & 15))) = f2bf(p[c][r]);
      }
      asm volatile("s_waitcnt lgkmcnt(0)" ::: "memory");
      // PV: X_h (16x16), K=64 over key positions
      f32x4 xacc = (f32x4){0.f, 0.f, 0.f, 0.f};
#pragma unroll
      for (int kc = 0; kc < 2; ++kc) {
        s16x8 pf = *(const s16x8*)(sp + swzP(arow, kc * 32 + ke));
        s16x8 vf = *(const s16x8*)(smem + SV_OFF + swz128(h * 16 + arow, kc * 32 + ke));
        xacc = __builtin_amdgcn_mfma_f32_16x16x32_bf16(pf, vf, xacc, 0, 0, 0);
      }
      // normalize + store X tile (bf16) over Qc (same-wave rows, disjoint cols)
#pragma unroll
      for (int r = 0; r < 4; ++r)
        *(short*)(smem + SQ_OFF + swz256(rb * 16 + (lane >> 4) * 4 + r, h * 16 + (lane & 15))) =
            f2bf(xacc[r] * inv[r]);
      asm volatile("s_waitcnt lgkmcnt(0)" ::: "memory");
    }
  }
  __syncthreads();  // b4: X visible

  // Phase 3: out = X @ W1^T + b1 (B-fragments preloaded in w1f)
  {
    f32x4 oacc[4];
#pragma unroll
    for (int rb = 0; rb < 4; ++rb) oacc[rb] = (f32x4){0.f, 0.f, 0.f, 0.f};
#pragma unroll
    for (int kk = 0; kk < 4; ++kk) {
#pragma unroll
      for (int rb = 0; rb < 4; ++rb) {
        s16x8 af = *(const s16x8*)(smem + SQ_OFF + swz256(rb * 16 + arow, kk * 32 + ke));
        oacc[rb] = __builtin_amdgcn_mfma_f32_16x16x32_bf16(af, w1f[kk], oacc[rb], 0, 0, 0);
      }
    }
    const float bv = b1[col];
#pragma unroll
    for (int rb = 0; rb < 4; ++rb)
#pragma unroll
      for (int r = 0; r < 4; ++r) {
        const int row = rb * 16 + (lane >> 4) * 4 + r;
        out[base + (size_t)row * Dd + col] = oacc[rb][r] + bv;
      }
  }
}

extern "C" void kernel_launch(void* const* d_in, const int* in_sizes, int n_in,
                              void* d_out, int out_size, void* d_ws, size_t ws_size,
                              hipStream_t stream) {
  (void)in_sizes; (void)n_in; (void)out_size; (void)ws_size;
  const float* query = (const float*)d_in[0];
  const float* key   = (const float*)d_in[1];
  const float* value = (const float*)d_in[2];
  // d_in[3] = mask (tril by construction -> causality hardcoded)
  const float* Wq = (const float*)d_in[4];
  const float* bq = (const float*)d_in[5];
  const float* Wk = (const float*)d_in[6];
  const float* bk = (const float*)d_in[7];
  const float* W0 = (const float*)d_in[8];
  const float* b0 = (const float*)d_in[9];
  const float* W1 = (const float*)d_in[10];
  const float* b1 = (const float*)d_in[11];
  float* out = (float*)d_out;
  short* wsb = (short*)d_ws;  // 131072 bf16 = 256 KB

  hipLaunchKernelGGL(prep_weights, dim3(512), dim3(256), 0, stream, Wq, Wk, W0, W1, wsb);
  hipLaunchKernelGGL(fused_attn, dim3(BN), dim3(512), 0, stream,
                     query, key, value, wsb, bq, bk, b0, b1, out);
}